// Round 8
// baseline (342.356 us; speedup 1.0000x reference)
//
#include <hip/hip_runtime.h>
#include <hip/hip_bf16.h>
#include <hip/hip_cooperative_groups.h>

namespace cg = cooperative_groups;

// ---------------------------------------------------------------------------
// Problem constants.  Inputs f32, output f32 (proven R4).
// ---------------------------------------------------------------------------
#define BATCH 2
#define CCH   512
#define NSEQ  2048
#define HEADS 16
#define DHEAD 64
#define HDIM  1024
#define ODIM  3072
// 8 * log2(e): folded into q-hat at the GEMM epilogue; M2 = this * max|qs*ks|.
#define QK_PRESCALE 11.541560327111707f

typedef short short4v __attribute__((ext_vector_type(4)));
typedef short short8 __attribute__((ext_vector_type(8)));
typedef float float4v __attribute__((ext_vector_type(4)));
typedef int   int4v   __attribute__((ext_vector_type(4)));

__device__ __forceinline__ unsigned short f2bf(float f) {          // RNE
    unsigned int u = __float_as_uint(f);
    return (unsigned short)((u + 0x7FFFu + ((u >> 16) & 1u)) >> 16);
}
__device__ __forceinline__ unsigned short f2bf_fast(float f) {     // round-half-up
    return (unsigned short)((__float_as_uint(f) + 0x8000u) >> 16);
}
__device__ __forceinline__ float fexp2(float x) {
#if __has_builtin(__builtin_amdgcn_exp2f)
    return __builtin_amdgcn_exp2f(x);
#else
    return exp2f(x);
#endif
}
// pack two f32 -> one dword of two bf16 (lo, hi)
__device__ __forceinline__ int pack_bf16(float lo, float hi) {
#if __has_builtin(__builtin_amdgcn_cvt_pk_bf16_f32)
    typedef __bf16 bf2_t __attribute__((ext_vector_type(2)));
    bf2_t v = __builtin_amdgcn_cvt_pk_bf16_f32(lo, hi);
    return __builtin_bit_cast(int, v);
#else
    return (int)f2bf_fast(lo) | ((int)(unsigned)f2bf_fast(hi) << 16);
#endif
}

typedef __attribute__((address_space(1))) const void* as1_cvp;
typedef __attribute__((address_space(3))) void* as3_vp;
__device__ __forceinline__ void cp16(const void* g, void* l) {
    __builtin_amdgcn_global_load_lds((as1_cvp)g, (as3_vp)l, 16, 0, 0);
}
// LDS XOR swizzle notes: see prior rounds (all reader/staging keys verified
// SQ_LDS_BANK_CONFLICT == 0 on hardware).
// ---------------------------------------------------------------------------
// R8: all four stages fused into ONE cooperative kernel (k_fused) with
// grid.sync() between phases — tests the launch-gap hypothesis (total
// 142 us vs ~47+~20+~13+~10 = 90 us of estimated kernel time).  Fallback
// to the proven 4-kernel path if cooperative launch is rejected.
// ---------------------------------------------------------------------------
// ======================= standalone kernels (fallback) =====================
__global__ __launch_bounds__(256) void k_prep(
    const float* __restrict__ Wqkv, const float* __restrict__ Wout,
    const float* __restrict__ x,
    const float* __restrict__ qs, const float* __restrict__ ks,
    unsigned short* __restrict__ Wqkvb, unsigned short* __restrict__ Woutb,
    unsigned short* __restrict__ xt, float* __restrict__ M) {
    const int bx = blockIdx.x;
    if (bx < 2048) {
        if (bx == 0 && threadIdx.x < 64) {
            int lane = threadIdx.x;
            float p = fabsf(qs[lane] * ks[lane]);
#pragma unroll
            for (int off = 1; off < 64; off <<= 1) p = fmaxf(p, __shfl_xor(p, off));
            if (lane == 0) *M = QK_PRESCALE * p;
        }
        int i4 = (bx * 256 + threadIdx.x) * 4;
        const float* src; unsigned short* dst; int idx;
        if (i4 < ODIM * CCH) { src = Wqkv; dst = Wqkvb; idx = i4; }
        else { src = Wout; dst = Woutb; idx = i4 - ODIM * CCH; }
        float4 v = *(const float4*)(src + idx);
        ushort4 o;
        o.x = f2bf(v.x); o.y = f2bf(v.y); o.z = f2bf(v.z); o.w = f2bf(v.w);
        *(ushort4*)(dst + idx) = o;
        return;
    }
    __shared__ unsigned short t[64][65];
    const int fx = bx - 2048;
    const int n0 = (fx & 31) * 64;
    const int c0 = ((fx >> 5) & 7) * 64;
    const int b  = fx >> 8;
    const int tr = threadIdx.x >> 6, tc = threadIdx.x & 63;
    const float* xs = x + (size_t)b * CCH * NSEQ;
    unsigned short* xd = xt + (size_t)b * NSEQ * CCH;
#pragma unroll
    for (int r = 0; r < 16; ++r) {
        int c = r * 4 + tr;
        t[c][tc] = f2bf(xs[(size_t)(c0 + c) * NSEQ + n0 + tc]);
    }
    __syncthreads();
#pragma unroll
    for (int r = 0; r < 16; ++r) {
        int n = r * 4 + tr;
        xd[(size_t)(n0 + n) * CCH + c0 + tc] = t[tc][n];
    }
}

__global__ __launch_bounds__(256) void k_gemm_qkv(
    const unsigned short* __restrict__ W, const unsigned short* __restrict__ xt,
    const float* __restrict__ qs, const float* __restrict__ ks,
    unsigned short* __restrict__ qh, unsigned short* __restrict__ kh,
    unsigned short* __restrict__ vb) {
    constexpr int K = CCH, N = NSEQ;
    __shared__ __align__(16) short smem[2 * 2 * 128 * 32];
    const int tid = threadIdx.x, wave = tid >> 6, lane = tid & 63;
    const int l15 = lane & 15, quad = lane >> 4;
    const int n0 = blockIdx.x * 128, m0 = blockIdx.y * 128, z = blockIdx.z;
    const short* Ab = (const short*)W + (size_t)m0 * K;
    const short* Bb = (const short*)xt + ((size_t)z * N + n0) * K;
    const int wm = wave >> 1, wn = wave & 1;
    const int srow = tid >> 2;
    const int cswz2 = (((tid & 3) ^ ((srow >> 1) & 3))) * 8;
    const int rchunk = ((quad ^ ((l15 >> 1) & 3))) * 8;

    float4v acc[4][4];
#pragma unroll
    for (int i = 0; i < 4; ++i)
#pragma unroll
        for (int j = 0; j < 4; ++j) acc[i][j] = (float4v){0.f, 0.f, 0.f, 0.f};

#define STAGEQ(K0_, BUF_) do {                                                   \
        short* bA = smem + (BUF_) * 8192 + wave * 512;                           \
        cp16(Ab + (size_t)srow * K + (K0_) + cswz2, bA);                         \
        cp16(Ab + (size_t)(64 + srow) * K + (K0_) + cswz2, bA + 2048);           \
        cp16(Bb + (size_t)srow * K + (K0_) + cswz2, bA + 4096);                  \
        cp16(Bb + (size_t)(64 + srow) * K + (K0_) + cswz2, bA + 6144);           \
    } while (0)

    STAGEQ(0, 0);
    __syncthreads();
    for (int ksi = 0; ksi < K / 32; ++ksi) {
        const int rb = ksi & 1;
        if (ksi + 1 < K / 32) STAGEQ((ksi + 1) * 32, rb ^ 1);
        const short* sA = smem + rb * 8192;
        const short* sB = sA + 4096;
        short8 af[4], bfr[4];
#pragma unroll
        for (int t = 0; t < 4; ++t) {
            af[t]  = *(const short8*)&sA[(wm * 64 + t * 16 + l15) * 32 + rchunk];
            bfr[t] = *(const short8*)&sB[(wn * 64 + t * 16 + l15) * 32 + rchunk];
        }
#pragma unroll
        for (int mt = 0; mt < 4; ++mt)
#pragma unroll
            for (int nt = 0; nt < 4; ++nt)
                acc[mt][nt] = __builtin_amdgcn_mfma_f32_16x16x32_bf16(af[mt], bfr[nt], acc[mt][nt], 0, 0, 0);
        __syncthreads();
    }
#undef STAGEQ

    const int co   = (m0 + wm * 64) >> 6;
    const int part = co >> 4;
    const int h    = co & 15;
    const int bh   = z * HEADS + h;
    short* myT = smem + wave * 4096;

    if (part < 2) {
        float inv[4];
#pragma unroll
        for (int nt = 0; nt < 4; ++nt) {
            float ss = 0.f;
#pragma unroll
            for (int mt = 0; mt < 4; ++mt)
#pragma unroll
                for (int r = 0; r < 4; ++r) ss += acc[mt][nt][r] * acc[mt][nt][r];
            ss += __shfl_xor(ss, 16);
            ss += __shfl_xor(ss, 32);
            inv[nt] = 1.0f / fmaxf(sqrtf(ss), 1e-12f);
        }
        const float* sc = part ? ks : qs;
        const float csc = part ? 1.0f : QK_PRESCALE;
#pragma unroll
        for (int mt = 0; mt < 4; ++mt) {
            const int db = mt * 16 + quad * 4;
            float4 s4 = *(const float4*)(sc + db);
            s4.x *= csc; s4.y *= csc; s4.z *= csc; s4.w *= csc;
#pragma unroll
            for (int nt = 0; nt < 4; ++nt) {
                int nl = nt * 16 + l15;
                short4v o;
                o.x = (short)f2bf(acc[mt][nt][0] * inv[nt] * s4.x);
                o.y = (short)f2bf(acc[mt][nt][1] * inv[nt] * s4.y);
                o.z = (short)f2bf(acc[mt][nt][2] * inv[nt] * s4.z);
                o.w = (short)f2bf(acc[mt][nt][3] * inv[nt] * s4.w);
                *(short4v*)&myT[nl * 64 + (((db >> 3) ^ (nl & 7)) << 3) + (db & 7)] = o;
            }
        }
        unsigned short* dst = (part ? kh : qh) + (size_t)bh * NSEQ * DHEAD
                              + (size_t)(n0 + wn * 64) * DHEAD;
#pragma unroll
        for (int pass = 0; pass < 8; ++pass) {
            int nl = pass * 8 + (lane >> 3), c = lane & 7;
            short8 vv = *(const short8*)&myT[nl * 64 + ((c ^ (nl & 7)) << 3)];
            *(short8*)&dst[(size_t)nl * DHEAD + c * 8] = vv;
        }
    } else {
#pragma unroll
        for (int mt = 0; mt < 4; ++mt)
#pragma unroll
            for (int nt = 0; nt < 4; ++nt) {
                int nl = nt * 16 + l15;
                int swc = nl >> 3, swo = nl & 7;
#pragma unroll
                for (int r = 0; r < 4; ++r) {
                    int d = mt * 16 + quad * 4 + r;
                    myT[d * 64 + ((swc ^ (d & 7)) << 3) + swo] = (short)f2bf(acc[mt][nt][r]);
                }
            }
        unsigned short* dst = vb + (size_t)bh * DHEAD * NSEQ + n0 + wn * 64;
#pragma unroll
        for (int pass = 0; pass < 8; ++pass) {
            int d = pass * 8 + (lane >> 3), c = lane & 7;
            short8 vv = *(const short8*)&myT[d * 64 + ((c ^ (d & 7)) << 3)];
            *(short8*)&dst[(size_t)d * NSEQ + c * 8] = vv;
        }
    }
}

#define KVB 32
__global__ __launch_bounds__(512, 4) void k_attn(
    const unsigned short* __restrict__ qh, const unsigned short* __restrict__ kh,
    const unsigned short* __restrict__ vb,
    unsigned short* __restrict__ aot, const float* __restrict__ Mptr) {
    __shared__ __align__(16) short Kt[2][4][KVB * 64];
    __shared__ __align__(16) short Vt[2][4][64 * KVB];
    const int tid = threadIdx.x, wave = tid >> 6, lane = tid & 63;
    const int grp = wave >> 2, w4 = wave & 3;
    const int gtid = tid & 255;
    const int l15 = lane & 15, quad = lane >> 4, q8 = quad * 8;
    const int flat = blockIdx.x;
    const int xcd = flat & 7, idx = flat >> 3;
    const int bh = xcd * 4 + (idx >> 4);
    const int i0 = (idx & 15) * 128;
    const int b = bh >> 4, h = bh & 15;
    const float Ms = *Mptr;
    const float4v mInit = (float4v){-Ms, -Ms, -Ms, -Ms};
    const int srow = gtid >> 3;
    const int kkey  = (srow & 3) | (((srow >> 3) & 1) << 2);
    const int cswzK = ((gtid & 7) ^ kkey) * 8;
    const int srowV = gtid >> 2;
    const int cswzV = ((gtid & 3) ^ ((srowV >> 1) & 3)) * 8;
    const int ksw = l15 & 7;
    const int kc0 = ((0 + quad) ^ ksw) * 8;
    const int kc1 = ((4 + quad) ^ ksw) * 8;
    const int vkr = (l15 >> 1) & 3;
    const int ar0 = (l15 >> 2) * 8 + (l15 & 3);
    const int ar1 = ar0 + 4;
    const int jbase = grp * (NSEQ / 2);

    short8 qf[2][2];
    {
        const short* qb = (const short*)qh + ((size_t)bh * NSEQ + i0 + w4 * 32) * DHEAD;
#pragma unroll
        for (int it = 0; it < 2; ++it) {
            qf[it][0] = *(const short8*)&qb[(it * 16 + l15) * DHEAD + q8];
            qf[it][1] = *(const short8*)&qb[(it * 16 + l15) * DHEAD + 32 + q8];
        }
    }

    float4v of[2][4];
#pragma unroll
    for (int it = 0; it < 2; ++it)
#pragma unroll
        for (int dt = 0; dt < 4; ++dt) of[it][dt] = (float4v){0.f, 0.f, 0.f, 0.f};
    float l_acc[2] = {0.f, 0.f};

    const short* kbase = (const short*)kh + ((size_t)bh * NSEQ + jbase) * DHEAD;
    const short* vbase = (const short*)vb + (size_t)bh * DHEAD * NSEQ + jbase;

#define STAGE(T_, B_) do {                                                       \
        cp16(kbase + (size_t)((T_) * KVB + srow) * DHEAD + cswzK,                \
             &Kt[grp][B_][w4 * 512]);                                            \
        cp16(vbase + (size_t)srowV * NSEQ + (T_) * KVB + cswzV,                  \
             &Vt[grp][B_][w4 * 512]);                                            \
    } while (0)

#define COMPUTE(CB_) do {                                                        \
        const short* Kb = &Kt[grp][CB_][0];                                      \
        const short* Vb = &Vt[grp][CB_][0];                                      \
        __builtin_amdgcn_s_setprio(1);                                           \
        short8 av[4];                                                            \
        _Pragma("unroll")                                                        \
        for (int dt = 0; dt < 4; ++dt)                                           \
            av[dt] = *(const short8*)&Vb[(dt * 16 + l15) * KVB + ((quad ^ vkr) * 8)]; \
        int4v pw[2];                                                             \
        _Pragma("unroll")                                                        \
        for (int t2 = 0; t2 < 2; ++t2) {                                         \
            const int arow = t2 ? ar1 : ar0;                                     \
            const short* kr = &Kb[arow * 64];                                    \
            short8 kf0 = *(const short8*)&kr[kc0];                               \
            short8 kf1 = *(const short8*)&kr[kc1];                               \
            _Pragma("unroll")                                                    \
            for (int it = 0; it < 2; ++it) {                                     \
                float4v s = mInit;                                               \
                s = __builtin_amdgcn_mfma_f32_16x16x32_bf16(kf0, qf[it][0], s, 0, 0, 0); \
                s = __builtin_amdgcn_mfma_f32_16x16x32_bf16(kf1, qf[it][1], s, 0, 0, 0); \
                float p0 = fexp2(s[0]);                                          \
                float p1 = fexp2(s[1]);                                          \
                float p2 = fexp2(s[2]);                                          \
                float p3 = fexp2(s[3]);                                          \
                l_acc[it] += (p0 + p1) + (p2 + p3);                              \
                pw[it][t2 * 2 + 0] = pack_bf16(p0, p1);                          \
                pw[it][t2 * 2 + 1] = pack_bf16(p2, p3);                          \
            }                                                                    \
        }                                                                        \
        {                                                                        \
            short8 pb0 = __builtin_bit_cast(short8, pw[0]);                      \
            short8 pb1 = __builtin_bit_cast(short8, pw[1]);                      \
            _Pragma("unroll")                                                    \
            for (int dt = 0; dt < 4; ++dt) {                                     \
                of[0][dt] = __builtin_amdgcn_mfma_f32_16x16x32_bf16(av[dt], pb0, of[0][dt], 0, 0, 0); \
                of[1][dt] = __builtin_amdgcn_mfma_f32_16x16x32_bf16(av[dt], pb1, of[1][dt], 0, 0, 0); \
            }                                                                    \
        }                                                                        \
        __builtin_amdgcn_s_setprio(0);                                           \
    } while (0)

#define WAITBAR(N_) do {                                                         \
        asm volatile("s_waitcnt vmcnt(" #N_ ")" ::: "memory");                   \
        __builtin_amdgcn_s_barrier();                                            \
        __builtin_amdgcn_sched_barrier(0);                                       \
    } while (0)

    constexpr int T = (NSEQ / 2) / KVB;
    STAGE(0, 0);
    STAGE(1, 1);
    for (int t = 0; t < T - 2; ++t) {
        STAGE(t + 2, (t + 2) & 3);
        WAITBAR(4);
        COMPUTE(t & 3);
    }
    WAITBAR(2);
    COMPUTE((T - 2) & 3);
    WAITBAR(0);
    COMPUTE((T - 1) & 3);
#undef STAGE
#undef COMPUTE
#undef WAITBAR

    float lred[2];
#pragma unroll
    for (int it = 0; it < 2; ++it) {
        float l = l_acc[it];
        l += __shfl_xor(l, 16);
        l += __shfl_xor(l, 32);
        lred[it] = l;
    }

    __syncthreads();

    float* F = (float*)&Kt[0][0][0];
    float* L = (float*)&Vt[0][0][0];
    if (grp == 1) {
#pragma unroll
        for (int it = 0; it < 2; ++it) {
#pragma unroll
            for (int dt = 0; dt < 4; ++dt)
                *(float4v*)&F[(((w4 * 2 + it) * 4 + dt) * 64 + lane) * 4] = of[it][dt];
            L[(w4 * 2 + it) * 64 + lane] = lred[it];
        }
    }
    __syncthreads();
    if (grp == 0) {
#pragma unroll
        for (int it = 0; it < 2; ++it) {
            float lt = lred[it] + L[(w4 * 2 + it) * 64 + lane];
            float inv = 1.0f / fmaxf(lt, 1e-30f);
            unsigned short* ob = aot + ((size_t)b * NSEQ + i0 + w4 * 32 + it * 16 + l15) * HDIM + h * DHEAD;
#pragma unroll
            for (int dt = 0; dt < 4; ++dt) {
                float4v p = *(const float4v*)&F[(((w4 * 2 + it) * 4 + dt) * 64 + lane) * 4];
                ushort4 o;
                o.x = f2bf((of[it][dt][0] + p[0]) * inv);
                o.y = f2bf((of[it][dt][1] + p[1]) * inv);
                o.z = f2bf((of[it][dt][2] + p[2]) * inv);
                o.w = f2bf((of[it][dt][3] + p[3]) * inv);
                *(ushort4*)&ob[dt * 16 + quad * 4] = o;
            }
        }
    }
}

__global__ __launch_bounds__(256) void k_gemm_out(
    const unsigned short* __restrict__ W, const unsigned short* __restrict__ aot,
    const float* __restrict__ bias, float* __restrict__ out) {
    constexpr int K = HDIM, N = NSEQ, M = CCH;
    __shared__ __align__(16) short lsm[2 * 2 * 64 * 64];
    const int tid = threadIdx.x, wave = tid >> 6, lane = tid & 63;
    const int l15 = lane & 15, quad = lane >> 4;
    const int n0 = blockIdx.x * 64, m0 = blockIdx.y * 64, z = blockIdx.z;
    const short* Ab = (const short*)W + (size_t)m0 * K;
    const short* Bb = (const short*)aot + ((size_t)z * N + n0) * K;
    const int wm = wave >> 1, wn = wave & 1;
    const int srow = tid >> 3;
    const int cswz = (((tid & 7) ^ (srow & 7))) * 8;
    const int sw7 = (l15 & 7);

    float4v acc[2][2];
#pragma unroll
    for (int i = 0; i < 2; ++i)
#pragma unroll
        for (int j = 0; j < 2; ++j) acc[i][j] = (float4v){0.f, 0.f, 0.f, 0.f};

#define STAGEO(K0_, BUF_) do {                                                   \
        short* bA = lsm + (BUF_) * 8192 + wave * 512;                            \
        cp16(Ab + (size_t)srow * K + (K0_) + cswz, bA);                          \
        cp16(Ab + (size_t)(srow + 32) * K + (K0_) + cswz, bA + 2048);            \
        cp16(Bb + (size_t)srow * K + (K0_) + cswz, bA + 4096);                   \
        cp16(Bb + (size_t)(srow + 32) * K + (K0_) + cswz, bA + 6144);            \
    } while (0)

    STAGEO(0, 0);
    __syncthreads();
    for (int ksi = 0; ksi < K / 64; ++ksi) {
        const int rb = ksi & 1;
        if (ksi + 1 < K / 64) STAGEO((ksi + 1) * 64, rb ^ 1);
        const short* sA = lsm + rb * 8192;
        const short* sB = sA + 4096;
        short8 af[2][2], bfr[2][2];
#pragma unroll
        for (int t = 0; t < 2; ++t)
#pragma unroll
            for (int kk = 0; kk < 2; ++kk) {
                af[t][kk]  = *(const short8*)&sA[(wm * 32 + t * 16 + l15) * 64 + ((kk * 4 + quad) ^ sw7) * 8];
                bfr[t][kk] = *(const short8*)&sB[(wn * 32 + t * 16 + l15) * 64 + ((kk * 4 + quad) ^ sw7) * 8];
            }
#pragma unroll
        for (int mt = 0; mt < 2; ++mt)
#pragma unroll
            for (int nt = 0; nt < 2; ++nt) {
                acc[mt][nt] = __builtin_amdgcn_mfma_f32_16x16x32_bf16(af[mt][0], bfr[nt][0], acc[mt][nt], 0, 0, 0);
                acc[mt][nt] = __builtin_amdgcn_mfma_f32_16x16x32_bf16(af[mt][1], bfr[nt][1], acc[mt][nt], 0, 0, 0);
            }
        __syncthreads();
    }
#undef STAGEO
    float* Co = out + (size_t)z * M * N;
#pragma unroll
    for (int mt = 0; mt < 2; ++mt)
#pragma unroll
        for (int nt = 0; nt < 2; ++nt) {
            int mrow = m0 + wm * 32 + mt * 16 + quad * 4;
#pragma unroll
            for (int r = 0; r < 4; ++r) {
                int mr = mrow + r;
                int nc = n0 + wn * 32 + nt * 16 + l15;
                Co[(size_t)mr * N + nc] = acc[mt][nt][r] + bias[mr];
            }
        }
}

// ============================ fused kernel =================================
// 512 blocks x 512 threads, 64 KB LDS, <=128 VGPR -> exactly 2 blocks/CU
// co-resident (512 = 256 CU x 2).  Phases separated by grid.sync().
// Barrier discipline: every __syncthreads() is OUTSIDE if(active) guards;
// per-real-block loop trip counts are identical across its two halves.
// ---------------------------------------------------------------------------
__global__ __launch_bounds__(512, 4) void k_fused(
    const float* __restrict__ Wqkv, const float* __restrict__ Wout,
    const float* __restrict__ x,
    const float* __restrict__ qs, const float* __restrict__ ks,
    unsigned short* __restrict__ Wqkvb, unsigned short* __restrict__ Woutb,
    unsigned short* __restrict__ xt, float* __restrict__ Mbuf,
    unsigned short* __restrict__ qh, unsigned short* __restrict__ kh,
    unsigned short* __restrict__ vb, unsigned short* __restrict__ aot,
    const float* __restrict__ bout, float* __restrict__ y) {
    __shared__ __align__(16) short SMEM[32768];   // 64 KB
    cg::grid_group grid = cg::this_grid();
    const int tid = threadIdx.x;
    const int rb = blockIdx.x;
    const int hf = tid >> 8;           // half-block id (0: waves 0-3, 1: 4-7)
    const int t256 = tid & 255;

    // ---------------- phase 0: prep (2560 virtual 256-thread blocks) -------
    {
        unsigned short* tt = (unsigned short*)(SMEM + hf * 16384); // [64][65]
        const int s = rb * 2 + hf;
        for (int k = 0; k < 3; ++k) {
            const int v = s + k * 1024;
            const bool a = v < 2560;
            if (a && v < 2048) {
                if (v == 0 && t256 < 64) {
                    int lane = t256;
                    float p = fabsf(qs[lane] * ks[lane]);
#pragma unroll
                    for (int off = 1; off < 64; off <<= 1) p = fmaxf(p, __shfl_xor(p, off));
                    if (lane == 0) *Mbuf = QK_PRESCALE * p;
                }
                int i4 = (v * 256 + t256) * 4;
                const float* src; unsigned short* dst; int idx;
                if (i4 < ODIM * CCH) { src = Wqkv; dst = Wqkvb; idx = i4; }
                else { src = Wout; dst = Woutb; idx = i4 - ODIM * CCH; }
                float4 vv = *(const float4*)(src + idx);
                ushort4 o;
                o.x = f2bf(vv.x); o.y = f2bf(vv.y); o.z = f2bf(vv.z); o.w = f2bf(vv.w);
                *(ushort4*)(dst + idx) = o;
            }
            const int fx = v - 2048;
            const int tr = t256 >> 6, tc = t256 & 63;
            if (a && v >= 2048) {
                const int n0 = (fx & 31) * 64;
                const int c0 = ((fx >> 5) & 7) * 64;
                const int b  = fx >> 8;
                const float* xs = x + (size_t)b * CCH * NSEQ;
#pragma unroll
                for (int r = 0; r < 16; ++r) {
                    int c = r * 4 + tr;
                    tt[c * 65 + tc] = f2bf(xs[(size_t)(c0 + c) * NSEQ + n0 + tc]);
                }
            }
            __syncthreads();
            if (a && v >= 2048) {
                const int n0 = (fx & 31) * 64;
                const int c0 = ((fx >> 5) & 7) * 64;
                const int b  = fx >> 8;
                unsigned short* xd = xt + (size_t)b * NSEQ * CCH;
#pragma unroll
                for (int r = 0; r < 16; ++r) {
                    int n = r * 4 + tr;
                    xd[(size_t)(n0 + n) * CCH + c0 + tc] = tt[tc * 65 + n];
                }
            }
            __syncthreads();
        }
    }
    grid.sync();

    // ---------------- phase 1: QKV GEMM (768 virtual 256-thread blocks) ----
    {
        const int s = rb * 2 + hf;
        bool act; int v;
        if (s < 512)      { act = true;  v = s; }
        else if (hf == 0) { act = true;  v = 512 + (rb - 256); }
        else              { act = false; v = 0; }
        constexpr int K = CCH, N = NSEQ;
        short* smq = SMEM + hf * 16384;   // 32 KB per half: 2 bufs x 8192
        const int wave = t256 >> 6, lane = t256 & 63;
        const int l15 = lane & 15, quad = lane >> 4;
        const int z = v / 384, rr = v % 384;
        const int m0 = (rr >> 4) * 128, n0 = (rr & 15) * 128;
        const short* Ab = (const short*)Wqkvb + (size_t)m0 * K;
        const short* Bb = (const short*)xt + ((size_t)z * N + n0) * K;
        const int wm = wave >> 1, wn = wave & 1;
        const int srow = t256 >> 2;
        const int cswz2 = (((t256 & 3) ^ ((srow >> 1) & 3))) * 8;
        const int rchunk = ((quad ^ ((l15 >> 1) & 3))) * 8;

        float4v acc[4][4];
#pragma unroll
        for (int i = 0; i < 4; ++i)
#pragma unroll
            for (int j = 0; j < 4; ++j) acc[i][j] = (float4v){0.f, 0.f, 0.f, 0.f};

#define FQ_STAGE(K0_, BUF_) do {                                                 \
        short* bA = smq + (BUF_) * 8192 + wave * 512;                            \
        cp16(Ab + (size_t)srow * K + (K0_) + cswz2, bA);                         \
        cp16(Ab + (size_t)(64 + srow) * K + (K0_) + cswz2, bA + 2048);           \
        cp16(Bb + (size_t)srow * K + (K0_) + cswz2, bA + 4096);                  \
        cp16(Bb + (size_t)(64 + srow) * K + (K0_) + cswz2, bA + 6144);           \
    } while (0)

        if (act) FQ_STAGE(0, 0);
        __syncthreads();
        for (int ksi = 0; ksi < K / 32; ++ksi) {
            if (act) {
                const int pb = ksi & 1;
                if (ksi + 1 < K / 32) FQ_STAGE((ksi + 1) * 32, pb ^ 1);
                const short* sA = smq + pb * 8192;
                const short* sB = sA + 4096;
                short8 af[4], bfr[4];
#pragma unroll
                for (int t = 0; t < 4; ++t) {
                    af[t]  = *(const short8*)&sA[(wm * 64 + t * 16 + l15) * 32 + rchunk];
                    bfr[t] = *(const short8*)&sB[(wn * 64 + t * 16 + l15) * 32 + rchunk];
                }
#pragma unroll
                for (int mt = 0; mt < 4; ++mt)
#pragma unroll
                    for (int nt = 0; nt < 4; ++nt)
                        acc[mt][nt] = __builtin_amdgcn_mfma_f32_16x16x32_bf16(af[mt], bfr[nt], acc[mt][nt], 0, 0, 0);
            }
            __syncthreads();
        }
#undef FQ_STAGE

        if (act) {
            const int co   = (m0 + wm * 64) >> 6;
            const int part = co >> 4;
            const int h    = co & 15;
            const int bh   = z * HEADS + h;
            short* myT = smq + wave * 4096;

            if (part < 2) {
                float inv[4];
#pragma unroll
                for (int nt = 0; nt < 4; ++nt) {
                    float ss = 0.f;
#pragma unroll
                    for (int mt = 0; mt < 4; ++mt)
#pragma unroll
                        for (int r = 0; r < 4; ++r) ss += acc[mt][nt][r] * acc[mt][nt][r];
                    ss += __shfl_xor(ss, 16);
                    ss += __shfl_xor(ss, 32);
                    inv[nt] = 1.0f / fmaxf(sqrtf(ss), 1e-12f);
                }
                const float* sc = part ? ks : qs;
                const float csc = part ? 1.0f : QK_PRESCALE;
#pragma unroll
                for (int mt = 0; mt < 4; ++mt) {
                    const int db = mt * 16 + quad * 4;
                    float4 s4 = *(const float4*)(sc + db);
                    s4.x *= csc; s4.y *= csc; s4.z *= csc; s4.w *= csc;
#pragma unroll
                    for (int nt = 0; nt < 4; ++nt) {
                        int nl = nt * 16 + l15;
                        short4v o;
                        o.x = (short)f2bf(acc[mt][nt][0] * inv[nt] * s4.x);
                        o.y = (short)f2bf(acc[mt][nt][1] * inv[nt] * s4.y);
                        o.z = (short)f2bf(acc[mt][nt][2] * inv[nt] * s4.z);
                        o.w = (short)f2bf(acc[mt][nt][3] * inv[nt] * s4.w);
                        *(short4v*)&myT[nl * 64 + (((db >> 3) ^ (nl & 7)) << 3) + (db & 7)] = o;
                    }
                }
                unsigned short* dst = (part ? kh : qh) + (size_t)bh * NSEQ * DHEAD
                                      + (size_t)(n0 + wn * 64) * DHEAD;
#pragma unroll
                for (int pass = 0; pass < 8; ++pass) {
                    int nl = pass * 8 + (lane >> 3), c = lane & 7;
                    short8 vv = *(const short8*)&myT[nl * 64 + ((c ^ (nl & 7)) << 3)];
                    *(short8*)&dst[(size_t)nl * DHEAD + c * 8] = vv;
                }
            } else {
#pragma unroll
                for (int mt = 0; mt < 4; ++mt)
#pragma unroll
                    for (int nt = 0; nt < 4; ++nt) {
                        int nl = nt * 16 + l15;
                        int swc = nl >> 3, swo = nl & 7;
#pragma unroll
                        for (int r = 0; r < 4; ++r) {
                            int d = mt * 16 + quad * 4 + r;
                            myT[d * 64 + ((swc ^ (d & 7)) << 3) + swo] = (short)f2bf(acc[mt][nt][r]);
                        }
                    }
                unsigned short* dst = vb + (size_t)bh * DHEAD * NSEQ + n0 + wn * 64;
#pragma unroll
                for (int pass = 0; pass < 8; ++pass) {
                    int d = pass * 8 + (lane >> 3), c = lane & 7;
                    short8 vv = *(const short8*)&myT[d * 64 + ((c ^ (d & 7)) << 3)];
                    *(short8*)&dst[(size_t)d * NSEQ + c * 8] = vv;
                }
            }
        }
    }
    grid.sync();

    // ---------------- phase 2: attention (v8, verbatim; block = rb) --------
    {
        short (*Kt)[4][KVB * 64] = (short (*)[4][KVB * 64])SMEM;
        short (*Vt)[4][64 * KVB] = (short (*)[4][64 * KVB])(SMEM + 16384);
        const int wave = tid >> 6, lane = tid & 63;
        const int grp2 = wave >> 2, w4 = wave & 3;
        const int gtid = tid & 255;
        const int l15 = lane & 15, quad = lane >> 4, q8 = quad * 8;
        const int flat = rb;
        const int xcd = flat & 7, idx = flat >> 3;
        const int bh = xcd * 4 + (idx >> 4);
        const int i0 = (idx & 15) * 128;
        const int b = bh >> 4, h = bh & 15;
        const float Ms = *Mbuf;
        const float4v mInit = (float4v){-Ms, -Ms, -Ms, -Ms};
        const int srow = gtid >> 3;
        const int kkey  = (srow & 3) | (((srow >> 3) & 1) << 2);
        const int cswzK = ((gtid & 7) ^ kkey) * 8;
        const int srowV = gtid >> 2;
        const int cswzV = ((gtid & 3) ^ ((srowV >> 1) & 3)) * 8;
        const int ksw = l15 & 7;
        const int kc0 = ((0 + quad) ^ ksw) * 8;
        const int kc1 = ((4 + quad) ^ ksw) * 8;
        const int vkr = (l15 >> 1) & 3;
        const int ar0 = (l15 >> 2) * 8 + (l15 & 3);
        const int ar1 = ar0 + 4;
        const int jbase = grp2 * (NSEQ / 2);

        short8 qf[2][2];
        {
            const short* qb = (const short*)qh + ((size_t)bh * NSEQ + i0 + w4 * 32) * DHEAD;
#pragma unroll
            for (int it = 0; it < 2; ++it) {
                qf[it][0] = *(const short8*)&qb[(it * 16 + l15) * DHEAD + q8];
                qf[it][1] = *(const short8*)&qb[(it * 16 + l15) * DHEAD + 32 + q8];
            }
        }

        float4v of[2][4];
#pragma unroll
        for (int it = 0; it < 2; ++it)
#pragma unroll
            for (int dt = 0; dt < 4; ++dt) of[it][dt] = (float4v){0.f, 0.f, 0.f, 0.f};
        float l_acc[2] = {0.f, 0.f};

        const short* kbase = (const short*)kh + ((size_t)bh * NSEQ + jbase) * DHEAD;
        const short* vbase = (const short*)vb + (size_t)bh * DHEAD * NSEQ + jbase;

#define FA_STAGE(T_, B_) do {                                                    \
        cp16(kbase + (size_t)((T_) * KVB + srow) * DHEAD + cswzK,                \
             &Kt[grp2][B_][w4 * 512]);                                           \
        cp16(vbase + (size_t)srowV * NSEQ + (T_) * KVB + cswzV,                  \
             &Vt[grp2][B_][w4 * 512]);                                           \
    } while (0)

#define FA_COMPUTE(CB_) do {                                                     \
        const short* Kb = &Kt[grp2][CB_][0];                                     \
        const short* Vb = &Vt[grp2][CB_][0];                                     \
        __builtin_amdgcn_s_setprio(1);                                           \
        short8 av[4];                                                            \
        _Pragma("unroll")                                                        \
        for (int dt = 0; dt < 4; ++dt)                                           \
            av[dt] = *(const short8*)&Vb[(dt * 16 + l15) * KVB + ((quad ^ vkr) * 8)]; \
        int4v pw[2];                                                             \
        _Pragma("unroll")                                                        \
        for (int t2 = 0; t2 < 2; ++t2) {                                         \
            const int arow = t2 ? ar1 : ar0;                                     \
            const short* kr = &Kb[arow * 64];                                    \
            short8 kf0 = *(const short8*)&kr[kc0];                               \
            short8 kf1 = *(const short8*)&kr[kc1];                               \
            _Pragma("unroll")                                                    \
            for (int it = 0; it < 2; ++it) {                                     \
                float4v s = mInit;                                               \
                s = __builtin_amdgcn_mfma_f32_16x16x32_bf16(kf0, qf[it][0], s, 0, 0, 0); \
                s = __builtin_amdgcn_mfma_f32_16x16x32_bf16(kf1, qf[it][1], s, 0, 0, 0); \
                float p0 = fexp2(s[0]);                                          \
                float p1 = fexp2(s[1]);                                          \
                float p2 = fexp2(s[2]);                                          \
                float p3 = fexp2(s[3]);                                          \
                l_acc[it] += (p0 + p1) + (p2 + p3);                              \
                pw[it][t2 * 2 + 0] = pack_bf16(p0, p1);                          \
                pw[it][t2 * 2 + 1] = pack_bf16(p2, p3);                          \
            }                                                                    \
        }                                                                        \
        {                                                                        \
            short8 pb0 = __builtin_bit_cast(short8, pw[0]);                      \
            short8 pb1 = __builtin_bit_cast(short8, pw[1]);                      \
            _Pragma("unroll")                                                    \
            for (int dt = 0; dt < 4; ++dt) {                                     \
                of[0][dt] = __builtin_amdgcn_mfma_f32_16x16x32_bf16(av[dt], pb0, of[0][dt], 0, 0, 0); \
                of[1][dt] = __builtin_amdgcn_mfma_f32_16x16x32_bf16(av[dt], pb1, of[1][dt], 0, 0, 0); \
            }                                                                    \
        }                                                                        \
        __builtin_amdgcn_s_setprio(0);                                           \
    } while (0)

#define FA_WAITBAR(N_) do {                                                      \
        asm volatile("s_waitcnt vmcnt(" #N_ ")" ::: "memory");                   \
        __builtin_amdgcn_s_barrier();                                            \
        __builtin_amdgcn_sched_barrier(0);                                       \
    } while (0)

        constexpr int T = (NSEQ / 2) / KVB;
        FA_STAGE(0, 0);
        FA_STAGE(1, 1);
        for (int t = 0; t < T - 2; ++t) {
            FA_STAGE(t + 2, (t + 2) & 3);
            FA_WAITBAR(4);
            FA_COMPUTE(t & 3);
        }
        FA_WAITBAR(2);
        FA_COMPUTE((T - 2) & 3);
        FA_WAITBAR(0);
        FA_COMPUTE((T - 1) & 3);
#undef FA_STAGE
#undef FA_COMPUTE
#undef FA_WAITBAR

        float lred[2];
#pragma unroll
        for (int it = 0; it < 2; ++it) {
            float l = l_acc[it];
            l += __shfl_xor(l, 16);
            l += __shfl_xor(l, 32);
            lred[it] = l;
        }

        __syncthreads();

        float* F = (float*)SMEM;
        float* L = (float*)(SMEM + 16384);
        if (grp2 == 1) {
#pragma unroll
            for (int it = 0; it < 2; ++it) {
#pragma unroll
                for (int dt = 0; dt < 4; ++dt)
                    *(float4v*)&F[(((w4 * 2 + it) * 4 + dt) * 64 + lane) * 4] = of[it][dt];
                L[(w4 * 2 + it) * 64 + lane] = lred[it];
            }
        }
        __syncthreads();
        if (grp2 == 0) {
#pragma unroll
            for (int it = 0; it < 2; ++it) {
                float lt = lred[it] + L[(w4 * 2 + it) * 64 + lane];
                float inv = 1.0f / fmaxf(lt, 1e-30f);
                unsigned short* ob = aot + ((size_t)b * NSEQ + i0 + w4 * 32 + it * 16 + l15) * HDIM + h * DHEAD;
#pragma unroll
                for (int dt = 0; dt < 4; ++dt) {
                    float4v p = *(const float4v*)&F[(((w4 * 2 + it) * 4 + dt) * 64 + lane) * 4];
                    ushort4 o;
                    o.x = f2bf((of[it][dt][0] + p[0]) * inv);
                    o.y = f2bf((of[it][dt][1] + p[1]) * inv);
                    o.z = f2bf((of[it][dt][2] + p[2]) * inv);
                    o.w = f2bf((of[it][dt][3] + p[3]) * inv);
                    *(ushort4*)&ob[dt * 16 + quad * 4] = o;
                }
            }
        }
    }
    grid.sync();

    // ---------------- phase 3: out GEMM (512 virtuals; half 0 active) ------
    {
        const bool act = (hf == 0);
        constexpr int K = HDIM, N = NSEQ, M = CCH;
        short* lsm = SMEM;   // half 0 uses first 32 KB
        const int wave = t256 >> 6, lane = t256 & 63;
        const int l15 = lane & 15, quad = lane >> 4;
        const int v = rb;
        const int z = v >> 8, rr = v & 255;
        const int n0 = (rr & 31) * 64, m0 = (rr >> 5) * 64;
        const short* Ab = (const short*)Woutb + (size_t)m0 * K;
        const short* Bb = (const short*)aot + ((size_t)z * N + n0) * K;
        const int wm = wave >> 1, wn = wave & 1;
        const int srow = t256 >> 3;
        const int cswz = (((t256 & 7) ^ (srow & 7))) * 8;
        const int sw7 = (l15 & 7);

        float4v acc[2][2];
#pragma unroll
        for (int i = 0; i < 2; ++i)
#pragma unroll
            for (int j = 0; j < 2; ++j) acc[i][j] = (float4v){0.f, 0.f, 0.f, 0.f};

#define FO_STAGE(K0_, BUF_) do {                                                 \
        short* bA = lsm + (BUF_) * 8192 + wave * 512;                            \
        cp16(Ab + (size_t)srow * K + (K0_) + cswz, bA);                          \
        cp16(Ab + (size_t)(srow + 32) * K + (K0_) + cswz, bA + 2048);            \
        cp16(Bb + (size_t)srow * K + (K0_) + cswz, bA + 4096);                   \
        cp16(Bb + (size_t)(srow + 32) * K + (K0_) + cswz, bA + 6144);            \
    } while (0)

        if (act) FO_STAGE(0, 0);
        __syncthreads();
        for (int ksi = 0; ksi < K / 64; ++ksi) {
            if (act) {
                const int pb = ksi & 1;
                if (ksi + 1 < K / 64) FO_STAGE((ksi + 1) * 64, pb ^ 1);
                const short* sA = lsm + pb * 8192;
                const short* sB = sA + 4096;
                short8 af[2][2], bfr[2][2];
#pragma unroll
                for (int t = 0; t < 2; ++t)
#pragma unroll
                    for (int kk = 0; kk < 2; ++kk) {
                        af[t][kk]  = *(const short8*)&sA[(wm * 32 + t * 16 + l15) * 64 + ((kk * 4 + quad) ^ sw7) * 8];
                        bfr[t][kk] = *(const short8*)&sB[(wn * 32 + t * 16 + l15) * 64 + ((kk * 4 + quad) ^ sw7) * 8];
                    }
#pragma unroll
                for (int mt = 0; mt < 2; ++mt)
#pragma unroll
                    for (int nt = 0; nt < 2; ++nt) {
                        acc[mt][nt] = __builtin_amdgcn_mfma_f32_16x16x32_bf16(af[mt][0], bfr[nt][0], acc[mt][nt], 0, 0, 0);
                        acc[mt][nt] = __builtin_amdgcn_mfma_f32_16x16x32_bf16(af[mt][1], bfr[nt][1], acc[mt][nt], 0, 0, 0);
                    }
            }
            __syncthreads();
        }
#undef FO_STAGE
        if (act) {
            float* Co = y + (size_t)z * M * N;
#pragma unroll
            for (int mt = 0; mt < 2; ++mt)
#pragma unroll
                for (int nt = 0; nt < 2; ++nt) {
                    int mrow = m0 + wm * 32 + mt * 16 + quad * 4;
#pragma unroll
                    for (int r = 0; r < 4; ++r) {
                        int mr = mrow + r;
                        int nc = n0 + wn * 32 + nt * 16 + l15;
                        Co[(size_t)mr * N + nc] = acc[mt][nt][r] + bout[mr];
                    }
                }
        }
    }
}

// ---------------------------------------------------------------------------
// Launch.  Inputs resolved by element count (f32).  Cooperative single-launch
// with fallback to the proven 4-kernel path.
// ---------------------------------------------------------------------------
extern "C" void kernel_launch(void* const* d_in, const int* in_sizes, int n_in,
                              void* d_out, int out_size, void* d_ws, size_t ws_size,
                              hipStream_t stream) {
    const float* x = nullptr; const float* Wqkv = nullptr;
    const float* qs = nullptr; const float* ks = nullptr;
    const float* Wout = nullptr; const float* bout = nullptr;
    for (int i = 0; i < n_in; ++i) {
        switch (in_sizes[i]) {
            case BATCH * CCH * NSEQ: x    = (const float*)d_in[i]; break;
            case ODIM * CCH:         Wqkv = (const float*)d_in[i]; break;
            case CCH * HDIM:         Wout = (const float*)d_in[i]; break;
            case CCH:                bout = (const float*)d_in[i]; break;
            case DHEAD: if (!qs) qs = (const float*)d_in[i]; else ks = (const float*)d_in[i]; break;
            default: break;
        }
    }
    float* y = (float*)d_out;

    char* ws = (char*)d_ws;
    float*          Mbuf  = (float*)(ws + 0);
    unsigned short* Wqkvb = (unsigned short*)(ws + 4096);
    unsigned short* Woutb = (unsigned short*)(ws + 3149824);
    unsigned short* xt    = (unsigned short*)(ws + 4198400);
    unsigned short* qh    = (unsigned short*)(ws + 8392704);
    unsigned short* kh    = (unsigned short*)(ws + 16781312);
    unsigned short* vb    = (unsigned short*)(ws + 25169920);
    unsigned short* aot   = (unsigned short*)(ws + 33558528);

    void* args[] = {
        (void*)&Wqkv, (void*)&Wout, (void*)&x, (void*)&qs, (void*)&ks,
        (void*)&Wqkvb, (void*)&Woutb, (void*)&xt, (void*)&Mbuf,
        (void*)&qh, (void*)&kh, (void*)&vb, (void*)&aot,
        (void*)&bout, (void*)&y
    };
    hipError_t err = hipLaunchCooperativeKernel(
        (const void*)k_fused, dim3(512), dim3(512), args, 0, stream);
    if (err != hipSuccess) {
        // fallback: proven 4-kernel path (R7)
        k_prep<<<dim3(2048 + 512), 256, 0, stream>>>(Wqkv, Wout, x, qs, ks, Wqkvb, Woutb, xt, Mbuf);
        k_gemm_qkv<<<dim3(NSEQ / 128, ODIM / 128, BATCH), 256, 0, stream>>>(Wqkvb, xt, qs, ks, qh, kh, vb);
        k_attn<<<dim3(512), 512, 0, stream>>>(qh, kh, vb, aot, Mbuf);
        k_gemm_out<<<dim3(NSEQ / 64, CCH / 64, BATCH), 256, 0, stream>>>(Woutb, aot, bout, y);
    }
}

// Round 9
// 141.976 us; speedup vs baseline: 2.4114x; 2.4114x over previous
//
#include <hip/hip_runtime.h>
#include <hip/hip_bf16.h>

// ---------------------------------------------------------------------------
// Problem constants.  Inputs f32, output f32 (proven R4).
// ---------------------------------------------------------------------------
#define BATCH 2
#define CCH   512
#define NSEQ  2048
#define HEADS 16
#define DHEAD 64
#define HDIM  1024
#define ODIM  3072
// 8 * log2(e): folded into q-hat at the GEMM epilogue; M2 = this * max|qs*ks|.
#define QK_PRESCALE 11.541560327111707f

typedef short short4v __attribute__((ext_vector_type(4)));
typedef short short8 __attribute__((ext_vector_type(8)));
typedef float float4v __attribute__((ext_vector_type(4)));
typedef int   int4v   __attribute__((ext_vector_type(4)));

__device__ __forceinline__ unsigned short f2bf(float f) {          // RNE
    unsigned int u = __float_as_uint(f);
    return (unsigned short)((u + 0x7FFFu + ((u >> 16) & 1u)) >> 16);
}
__device__ __forceinline__ unsigned short f2bf_fast(float f) {     // round-half-up
    return (unsigned short)((__float_as_uint(f) + 0x8000u) >> 16);
}
__device__ __forceinline__ float fexp2(float x) {
#if __has_builtin(__builtin_amdgcn_exp2f)
    return __builtin_amdgcn_exp2f(x);
#else
    return exp2f(x);
#endif
}
// pack two f32 -> one dword of two bf16 (lo, hi)
__device__ __forceinline__ int pack_bf16(float lo, float hi) {
#if __has_builtin(__builtin_amdgcn_cvt_pk_bf16_f32)
    typedef __bf16 bf2_t __attribute__((ext_vector_type(2)));
    bf2_t v = __builtin_amdgcn_cvt_pk_bf16_f32(lo, hi);
    return __builtin_bit_cast(int, v);
#else
    return (int)f2bf_fast(lo) | ((int)(unsigned)f2bf_fast(hi) << 16);
#endif
}

typedef __attribute__((address_space(1))) const void* as1_cvp;
typedef __attribute__((address_space(3))) void* as3_vp;
__device__ __forceinline__ void cp16(const void* g, void* l) {
    __builtin_amdgcn_global_load_lds((as1_cvp)g, (as3_vp)l, 16, 0, 0);
}
// LDS XOR swizzle (verified SQ_LDS_BANK_CONFLICT == 0 on hardware): slot
// (row,chunk) holds global (row, chunk ^ key(row)); staging lane fetches
// global chunk (lane&7)^key(row).  Kt in k_attn uses the fine key
// (row&3)|(((row>>3)&1)<<2) so the PERMUTED A-row reads fold to l15&7.
// 32-short rows (qkv BK=32 tiles, attn Vt) use key(row) = (row>>1)&3.
//
// R9: revert to R6 (best measured, 142.2 us); attn main loop unrolled x4
// (ring indices become literals) + incremental staging pointers (cuts
// per-step 64-bit address recomputation).  Semantics identical to v8.
// ---------------------------------------------------------------------------
// k_prep: blocks [0,2048) convert Wqkv|Wout f32->bf16; blocks [2048,2560)
// transpose x [b][c][n] -> xt [b][n][c].  Block 0 also computes M2.
// ---------------------------------------------------------------------------
__global__ __launch_bounds__(256) void k_prep(
    const float* __restrict__ Wqkv, const float* __restrict__ Wout,
    const float* __restrict__ x,
    const float* __restrict__ qs, const float* __restrict__ ks,
    unsigned short* __restrict__ Wqkvb, unsigned short* __restrict__ Woutb,
    unsigned short* __restrict__ xt, float* __restrict__ M) {
    const int bx = blockIdx.x;
    if (bx < 2048) {
        if (bx == 0 && threadIdx.x < 64) {
            int lane = threadIdx.x;
            float p = fabsf(qs[lane] * ks[lane]);
#pragma unroll
            for (int off = 1; off < 64; off <<= 1) p = fmaxf(p, __shfl_xor(p, off));
            if (lane == 0) *M = QK_PRESCALE * p;
        }
        int i4 = (bx * 256 + threadIdx.x) * 4;
        const float* src; unsigned short* dst; int idx;
        if (i4 < ODIM * CCH) { src = Wqkv; dst = Wqkvb; idx = i4; }
        else { src = Wout; dst = Woutb; idx = i4 - ODIM * CCH; }
        float4 v = *(const float4*)(src + idx);
        ushort4 o;
        o.x = f2bf(v.x); o.y = f2bf(v.y); o.z = f2bf(v.z); o.w = f2bf(v.w);
        *(ushort4*)(dst + idx) = o;
        return;
    }
    __shared__ unsigned short t[64][65];
    const int fx = bx - 2048;
    const int n0 = (fx & 31) * 64;
    const int c0 = ((fx >> 5) & 7) * 64;
    const int b  = fx >> 8;
    const int tr = threadIdx.x >> 6, tc = threadIdx.x & 63;
    const float* xs = x + (size_t)b * CCH * NSEQ;
    unsigned short* xd = xt + (size_t)b * NSEQ * CCH;
#pragma unroll
    for (int r = 0; r < 16; ++r) {
        int c = r * 4 + tr;
        t[c][tc] = f2bf(xs[(size_t)(c0 + c) * NSEQ + n0 + tc]);
    }
    __syncthreads();
#pragma unroll
    for (int r = 0; r < 16; ++r) {
        int n = r * 4 + tr;
        xd[(size_t)(n0 + n) * CCH + c0 + tc] = t[tc][n];
    }
}

// ---------------------------------------------------------------------------
// k_gemm_qkv v2 (R6 measured-best): fused QKV GEMM + l2-norm/scale + head
// repack.  BK=32, double-buffered LDS, STAGE(t+1) before compute(t), one
// barrier per k-step.  Epilogue: per-wave LDS transpose, 128B-row stores.
// ---------------------------------------------------------------------------
__global__ __launch_bounds__(256) void k_gemm_qkv(
    const unsigned short* __restrict__ W, const unsigned short* __restrict__ xt,
    const float* __restrict__ qs, const float* __restrict__ ks,
    unsigned short* __restrict__ qh, unsigned short* __restrict__ kh,
    unsigned short* __restrict__ vb) {
    constexpr int K = CCH, N = NSEQ;
    // [buf][A:4096 | B:4096] shorts; buf stride 8192 shorts (16 KB)
    __shared__ __align__(16) short smem[2 * 2 * 128 * 32];
    const int tid = threadIdx.x, wave = tid >> 6, lane = tid & 63;
    const int l15 = lane & 15, quad = lane >> 4;
    const int n0 = blockIdx.x * 128, m0 = blockIdx.y * 128, z = blockIdx.z;
    const short* Ab = (const short*)W + (size_t)m0 * K;
    const short* Bb = (const short*)xt + ((size_t)z * N + n0) * K;
    const int wm = wave >> 1, wn = wave & 1;
    const int srow = tid >> 2;
    const int cswz2 = (((tid & 3) ^ ((srow >> 1) & 3))) * 8;
    const int rchunk = ((quad ^ ((l15 >> 1) & 3))) * 8;

    float4v acc[4][4];
#pragma unroll
    for (int i = 0; i < 4; ++i)
#pragma unroll
        for (int j = 0; j < 4; ++j) acc[i][j] = (float4v){0.f, 0.f, 0.f, 0.f};

#define STAGEQ(K0_, BUF_) do {                                                   \
        short* bA = smem + (BUF_) * 8192 + wave * 512;                           \
        cp16(Ab + (size_t)srow * K + (K0_) + cswz2, bA);                         \
        cp16(Ab + (size_t)(64 + srow) * K + (K0_) + cswz2, bA + 2048);           \
        cp16(Bb + (size_t)srow * K + (K0_) + cswz2, bA + 4096);                  \
        cp16(Bb + (size_t)(64 + srow) * K + (K0_) + cswz2, bA + 6144);           \
    } while (0)

    STAGEQ(0, 0);
    __syncthreads();
    for (int ksi = 0; ksi < K / 32; ++ksi) {
        const int rb = ksi & 1;
        if (ksi + 1 < K / 32) STAGEQ((ksi + 1) * 32, rb ^ 1);
        const short* sA = smem + rb * 8192;
        const short* sB = sA + 4096;
        short8 af[4], bfr[4];
#pragma unroll
        for (int t = 0; t < 4; ++t) {
            af[t]  = *(const short8*)&sA[(wm * 64 + t * 16 + l15) * 32 + rchunk];
            bfr[t] = *(const short8*)&sB[(wn * 64 + t * 16 + l15) * 32 + rchunk];
        }
#pragma unroll
        for (int mt = 0; mt < 4; ++mt)
#pragma unroll
            for (int nt = 0; nt < 4; ++nt)
                acc[mt][nt] = __builtin_amdgcn_mfma_f32_16x16x32_bf16(af[mt], bfr[nt], acc[mt][nt], 0, 0, 0);
        __syncthreads();   // drains the just-issued STAGE after MFMA cover
    }
#undef STAGEQ

    const int co   = (m0 + wm * 64) >> 6;
    const int part = co >> 4;               // 0=q, 1=k, 2=v
    const int h    = co & 15;
    const int bh   = z * HEADS + h;
    short* myT = smem + wave * 4096;

    if (part < 2) {
        float inv[4];
#pragma unroll
        for (int nt = 0; nt < 4; ++nt) {
            float ss = 0.f;
#pragma unroll
            for (int mt = 0; mt < 4; ++mt)
#pragma unroll
                for (int r = 0; r < 4; ++r) ss += acc[mt][nt][r] * acc[mt][nt][r];
            ss += __shfl_xor(ss, 16);
            ss += __shfl_xor(ss, 32);
            inv[nt] = 1.0f / fmaxf(sqrtf(ss), 1e-12f);
        }
        const float* sc = part ? ks : qs;
        const float csc = part ? 1.0f : QK_PRESCALE;
#pragma unroll
        for (int mt = 0; mt < 4; ++mt) {
            const int db = mt * 16 + quad * 4;
            float4 s4 = *(const float4*)(sc + db);
            s4.x *= csc; s4.y *= csc; s4.z *= csc; s4.w *= csc;
#pragma unroll
            for (int nt = 0; nt < 4; ++nt) {
                int nl = nt * 16 + l15;
                short4v o;
                o.x = (short)f2bf(acc[mt][nt][0] * inv[nt] * s4.x);
                o.y = (short)f2bf(acc[mt][nt][1] * inv[nt] * s4.y);
                o.z = (short)f2bf(acc[mt][nt][2] * inv[nt] * s4.z);
                o.w = (short)f2bf(acc[mt][nt][3] * inv[nt] * s4.w);
                *(short4v*)&myT[nl * 64 + (((db >> 3) ^ (nl & 7)) << 3) + (db & 7)] = o;
            }
        }
        unsigned short* dst = (part ? kh : qh) + (size_t)bh * NSEQ * DHEAD
                              + (size_t)(n0 + wn * 64) * DHEAD;
#pragma unroll
        for (int pass = 0; pass < 8; ++pass) {
            int nl = pass * 8 + (lane >> 3), c = lane & 7;
            short8 vv = *(const short8*)&myT[nl * 64 + ((c ^ (nl & 7)) << 3)];
            *(short8*)&dst[(size_t)nl * DHEAD + c * 8] = vv;
        }
    } else {
#pragma unroll
        for (int mt = 0; mt < 4; ++mt)
#pragma unroll
            for (int nt = 0; nt < 4; ++nt) {
                int nl = nt * 16 + l15;
                int swc = nl >> 3, swo = nl & 7;
#pragma unroll
                for (int r = 0; r < 4; ++r) {
                    int d = mt * 16 + quad * 4 + r;
                    myT[d * 64 + ((swc ^ (d & 7)) << 3) + swo] = (short)f2bf(acc[mt][nt][r]);
                }
            }
        unsigned short* dst = vb + (size_t)bh * DHEAD * NSEQ + n0 + wn * 64;
#pragma unroll
        for (int pass = 0; pass < 8; ++pass) {
            int d = pass * 8 + (lane >> 3), c = lane & 7;
            short8 vv = *(const short8*)&myT[d * 64 + ((c ^ (d & 7)) << 3)];
            *(short8*)&dst[(size_t)d * NSEQ + c * 8] = vv;
        }
    }
}

// ---------------------------------------------------------------------------
// k_attn v8.1: v8 (best measured 47.2 us, 0 conflicts) with the main loop
// unrolled x4 (ring indices (t+2)&3 / t&3 become literals -> LDS bases fold
// to immediates) and incremental global staging pointers (kp += KVB*DHEAD,
// vp += KVB replace per-step mul + 64-bit add chains).  Sync/vmcnt schedule
// byte-identical to v8: STAGE(t+2) -> vmcnt(4) -> s_barrier -> COMPUTE(t).
// ---------------------------------------------------------------------------
#define KVB 32
__global__ __launch_bounds__(512, 4) void k_attn(
    const unsigned short* __restrict__ qh, const unsigned short* __restrict__ kh,
    const unsigned short* __restrict__ vb,
    unsigned short* __restrict__ aot, const float* __restrict__ Mptr) {
    __shared__ __align__(16) short Kt[2][4][KVB * 64];   // [group][stage] 4KB
    __shared__ __align__(16) short Vt[2][4][64 * KVB];   // [group][stage] 4KB
    const int tid = threadIdx.x, wave = tid >> 6, lane = tid & 63;
    const int grp = wave >> 2, w4 = wave & 3;
    const int gtid = tid & 255;
    const int l15 = lane & 15, quad = lane >> 4, q8 = quad * 8;
    const int flat = blockIdx.x;
    const int xcd = flat & 7, idx = flat >> 3;
    const int bh = xcd * 4 + (idx >> 4);
    const int i0 = (idx & 15) * 128;
    const int b = bh >> 4, h = bh & 15;
    const float Ms = *Mptr;
    const float4v mInit = (float4v){-Ms, -Ms, -Ms, -Ms};
    const int srow = gtid >> 3;
    // Kt fine swizzle key (staging side): (row&3)|(((row>>3)&1)<<2)
    const int kkey  = (srow & 3) | (((srow >> 3) & 1) << 2);
    const int cswzK = ((gtid & 7) ^ kkey) * 8;
    // V staging: 64 rows x 4 chunks (64B rows); key = (row>>1)&3
    const int srowV = gtid >> 2;
    const int cswzV = ((gtid & 3) ^ ((srowV >> 1) & 3)) * 8;
    // reader-side keys (lane-constant)
    const int ksw = l15 & 7;
    const int kc0 = ((0 + quad) ^ ksw) * 8;
    const int kc1 = ((4 + quad) ^ ksw) * 8;
    const int vkr = (l15 >> 1) & 3;
    // permuted A-row indices within the 32-j tile for the two S^T sub-tiles
    const int ar0 = (l15 >> 2) * 8 + (l15 & 3);
    const int ar1 = ar0 + 4;
    const int jbase = grp * (NSEQ / 2);

    // Q fragments (B-operand of S^T): rows it*16+l15, d-slices quad*8
    short8 qf[2][2];
    {
        const short* qb = (const short*)qh + ((size_t)bh * NSEQ + i0 + w4 * 32) * DHEAD;
#pragma unroll
        for (int it = 0; it < 2; ++it) {
            qf[it][0] = *(const short8*)&qb[(it * 16 + l15) * DHEAD + q8];
            qf[it][1] = *(const short8*)&qb[(it * 16 + l15) * DHEAD + 32 + q8];
        }
    }

    float4v of[2][4];
#pragma unroll
    for (int it = 0; it < 2; ++it)
#pragma unroll
        for (int dt = 0; dt < 4; ++dt) of[it][dt] = (float4v){0.f, 0.f, 0.f, 0.f};
    float l_acc[2] = {0.f, 0.f};

    const short* kbase = (const short*)kh + ((size_t)bh * NSEQ + jbase) * DHEAD;
    const short* vbase = (const short*)vb + (size_t)bh * DHEAD * NSEQ + jbase;

#define COMPUTE(CB_) do {                                                        \
        const short* Kb = &Kt[grp][CB_][0];                                      \
        const short* Vb = &Vt[grp][CB_][0];                                      \
        __builtin_amdgcn_s_setprio(1);                                           \
        short8 av[4];                                                            \
        _Pragma("unroll")                                                        \
        for (int dt = 0; dt < 4; ++dt)                                           \
            av[dt] = *(const short8*)&Vb[(dt * 16 + l15) * KVB + ((quad ^ vkr) * 8)]; \
        int4v pw[2];                                                             \
        _Pragma("unroll")                                                        \
        for (int t2 = 0; t2 < 2; ++t2) {                                         \
            const int arow = t2 ? ar1 : ar0;                                     \
            const short* kr = &Kb[arow * 64];                                    \
            short8 kf0 = *(const short8*)&kr[kc0];                               \
            short8 kf1 = *(const short8*)&kr[kc1];                               \
            _Pragma("unroll")                                                    \
            for (int it = 0; it < 2; ++it) {                                     \
                float4v s = mInit;                                               \
                s = __builtin_amdgcn_mfma_f32_16x16x32_bf16(kf0, qf[it][0], s, 0, 0, 0); \
                s = __builtin_amdgcn_mfma_f32_16x16x32_bf16(kf1, qf[it][1], s, 0, 0, 0); \
                float p0 = fexp2(s[0]);                                          \
                float p1 = fexp2(s[1]);                                          \
                float p2 = fexp2(s[2]);                                          \
                float p3 = fexp2(s[3]);                                          \
                l_acc[it] += (p0 + p1) + (p2 + p3);                              \
                pw[it][t2 * 2 + 0] = pack_bf16(p0, p1);                          \
                pw[it][t2 * 2 + 1] = pack_bf16(p2, p3);                          \
            }                                                                    \
        }                                                                        \
        {                                                                        \
            short8 pb0 = __builtin_bit_cast(short8, pw[0]);                      \
            short8 pb1 = __builtin_bit_cast(short8, pw[1]);                      \
            _Pragma("unroll")                                                    \
            for (int dt = 0; dt < 4; ++dt) {                                     \
                of[0][dt] = __builtin_amdgcn_mfma_f32_16x16x32_bf16(av[dt], pb0, of[0][dt], 0, 0, 0); \
                of[1][dt] = __builtin_amdgcn_mfma_f32_16x16x32_bf16(av[dt], pb1, of[1][dt], 0, 0, 0); \
            }                                                                    \
        }                                                                        \
        __builtin_amdgcn_s_setprio(0);                                           \
    } while (0)

#define WAITBAR(N_) do {                                                         \
        asm volatile("s_waitcnt vmcnt(" #N_ ")" ::: "memory");                   \
        __builtin_amdgcn_s_barrier();                                            \
        __builtin_amdgcn_sched_barrier(0);                                       \
    } while (0)

    constexpr int T = (NSEQ / 2) / KVB;   // 32 steps per group
    // prologue: stage tiles 0 and 1
    cp16(kbase + (size_t)(0 * KVB + srow) * DHEAD + cswzK, &Kt[grp][0][w4 * 512]);
    cp16(vbase + (size_t)srowV * NSEQ + 0 * KVB + cswzV,   &Vt[grp][0][w4 * 512]);
    cp16(kbase + (size_t)(1 * KVB + srow) * DHEAD + cswzK, &Kt[grp][1][w4 * 512]);
    cp16(vbase + (size_t)srowV * NSEQ + 1 * KVB + cswzV,   &Vt[grp][1][w4 * 512]);
    // incremental staging pointers (point at tile t+2's slot for t=0)
    const short* kp = kbase + (size_t)(2 * KVB + srow) * DHEAD + cswzK;
    const short* vp = vbase + (size_t)srowV * NSEQ + 2 * KVB + cswzV;
#pragma unroll 4
    for (int t = 0; t < T - 2; ++t) {
        cp16(kp, &Kt[grp][(t + 2) & 3][w4 * 512]);
        cp16(vp, &Vt[grp][(t + 2) & 3][w4 * 512]);
        kp += KVB * DHEAD;
        vp += KVB;
        WAITBAR(4);
        COMPUTE(t & 3);
    }
    WAITBAR(2);
    COMPUTE((T - 2) & 3);
    WAITBAR(0);
    COMPUTE((T - 1) & 3);
#undef COMPUTE
#undef WAITBAR

    // quad-reduce l per i-row (all lanes end up holding their row's l)
    float lred[2];
#pragma unroll
    for (int it = 0; it < 2; ++it) {
        float l = l_acc[it];
        l += __shfl_xor(l, 16);
        l += __shfl_xor(l, 32);
        lred[it] = l;
    }

    __syncthreads();   // all compute done before LDS is repurposed

    // cross-group combine: group 1 dumps unnormalized partials into the (now
    // idle) K/V LDS space; group 0 adds, normalizes once, stores bf16 O^T.
    float* F = (float*)&Kt[0][0][0];   // 32 KB: of fragments
    float* L = (float*)&Vt[0][0][0];   // 2 KB: l partials
    if (grp == 1) {
#pragma unroll
        for (int it = 0; it < 2; ++it) {
#pragma unroll
            for (int dt = 0; dt < 4; ++dt)
                *(float4v*)&F[(((w4 * 2 + it) * 4 + dt) * 64 + lane) * 4] = of[it][dt];
            L[(w4 * 2 + it) * 64 + lane] = lred[it];
        }
    }
    __syncthreads();
    if (grp == 0) {
#pragma unroll
        for (int it = 0; it < 2; ++it) {
            float lt = lred[it] + L[(w4 * 2 + it) * 64 + lane];
            float inv = 1.0f / fmaxf(lt, 1e-30f);
            unsigned short* ob = aot + ((size_t)b * NSEQ + i0 + w4 * 32 + it * 16 + l15) * HDIM + h * DHEAD;
#pragma unroll
            for (int dt = 0; dt < 4; ++dt) {
                float4v p = *(const float4v*)&F[(((w4 * 2 + it) * 4 + dt) * 64 + lane) * 4];
                ushort4 o;
                o.x = f2bf((of[it][dt][0] + p[0]) * inv);
                o.y = f2bf((of[it][dt][1] + p[1]) * inv);
                o.z = f2bf((of[it][dt][2] + p[2]) * inv);
                o.w = f2bf((of[it][dt][3] + p[3]) * inv);
                *(ushort4*)&ob[dt * 16 + quad * 4] = o;
            }
        }
    }
}

// ---------------------------------------------------------------------------
// k_gemm_out v2 (R6 measured-best): 64x64 tiles, double-buffered LDS,
// STAGE(t+1) before compute(t), one barrier per k-step.
// y[b][o][n] f32 = sum_c Wout[o][c]*aot[b][n][c] + bout[o]
// ---------------------------------------------------------------------------
__global__ __launch_bounds__(256) void k_gemm_out(
    const unsigned short* __restrict__ W, const unsigned short* __restrict__ aot,
    const float* __restrict__ bias, float* __restrict__ out) {
    constexpr int K = HDIM, N = NSEQ, M = CCH;
    // [buf][A:4096 | B:4096] shorts; buf stride 8192 shorts (16 KB)
    __shared__ __align__(16) short lsm[2 * 2 * 64 * 64];
    const int tid = threadIdx.x, wave = tid >> 6, lane = tid & 63;
    const int l15 = lane & 15, quad = lane >> 4;
    const int n0 = blockIdx.x * 64, m0 = blockIdx.y * 64, z = blockIdx.z;
    const short* Ab = (const short*)W + (size_t)m0 * K;
    const short* Bb = (const short*)aot + ((size_t)z * N + n0) * K;
    const int wm = wave >> 1, wn = wave & 1;
    const int srow = tid >> 3;                                   // 0..31
    const int cswz = (((tid & 7) ^ (srow & 7))) * 8;             // key = row&7
    const int sw7 = (l15 & 7);

    float4v acc[2][2];
#pragma unroll
    for (int i = 0; i < 2; ++i)
#pragma unroll
        for (int j = 0; j < 2; ++j) acc[i][j] = (float4v){0.f, 0.f, 0.f, 0.f};

#define STAGEO(K0_, BUF_) do {                                                   \
        short* bA = lsm + (BUF_) * 8192 + wave * 512;                            \
        cp16(Ab + (size_t)srow * K + (K0_) + cswz, bA);                          \
        cp16(Ab + (size_t)(srow + 32) * K + (K0_) + cswz, bA + 2048);            \
        cp16(Bb + (size_t)srow * K + (K0_) + cswz, bA + 4096);                   \
        cp16(Bb + (size_t)(srow + 32) * K + (K0_) + cswz, bA + 6144);            \
    } while (0)

    STAGEO(0, 0);
    __syncthreads();
    for (int ksi = 0; ksi < K / 64; ++ksi) {
        const int rb = ksi & 1;
        if (ksi + 1 < K / 64) STAGEO((ksi + 1) * 64, rb ^ 1);
        const short* sA = lsm + rb * 8192;
        const short* sB = sA + 4096;
        short8 af[2][2], bfr[2][2];
#pragma unroll
        for (int t = 0; t < 2; ++t)
#pragma unroll
            for (int kk = 0; kk < 2; ++kk) {
                af[t][kk]  = *(const short8*)&sA[(wm * 32 + t * 16 + l15) * 64 + ((kk * 4 + quad) ^ sw7) * 8];
                bfr[t][kk] = *(const short8*)&sB[(wn * 32 + t * 16 + l15) * 64 + ((kk * 4 + quad) ^ sw7) * 8];
            }
#pragma unroll
        for (int mt = 0; mt < 2; ++mt)
#pragma unroll
            for (int nt = 0; nt < 2; ++nt) {
                acc[mt][nt] = __builtin_amdgcn_mfma_f32_16x16x32_bf16(af[mt][0], bfr[nt][0], acc[mt][nt], 0, 0, 0);
                acc[mt][nt] = __builtin_amdgcn_mfma_f32_16x16x32_bf16(af[mt][1], bfr[nt][1], acc[mt][nt], 0, 0, 0);
            }
        __syncthreads();   // drains the just-issued STAGE after MFMA cover
    }
#undef STAGEO
    float* Co = out + (size_t)z * M * N;
#pragma unroll
    for (int mt = 0; mt < 2; ++mt)
#pragma unroll
        for (int nt = 0; nt < 2; ++nt) {
            int mrow = m0 + wm * 32 + mt * 16 + quad * 4;
#pragma unroll
            for (int r = 0; r < 4; ++r) {
                int mr = mrow + r;
                int nc = n0 + wn * 32 + nt * 16 + l15;
                Co[(size_t)mr * N + nc] = acc[mt][nt][r] + bias[mr];
            }
        }
}

// ---------------------------------------------------------------------------
// Launch.  Inputs resolved by element count (f32).
// ---------------------------------------------------------------------------
extern "C" void kernel_launch(void* const* d_in, const int* in_sizes, int n_in,
                              void* d_out, int out_size, void* d_ws, size_t ws_size,
                              hipStream_t stream) {
    const float* x = nullptr; const float* Wqkv = nullptr;
    const float* qs = nullptr; const float* ks = nullptr;
    const float* Wout = nullptr; const float* bout = nullptr;
    for (int i = 0; i < n_in; ++i) {
        switch (in_sizes[i]) {
            case BATCH * CCH * NSEQ: x    = (const float*)d_in[i]; break;
            case ODIM * CCH:         Wqkv = (const float*)d_in[i]; break;
            case CCH * HDIM:         Wout = (const float*)d_in[i]; break;
            case CCH:                bout = (const float*)d_in[i]; break;
            case DHEAD: if (!qs) qs = (const float*)d_in[i]; else ks = (const float*)d_in[i]; break;
            default: break;
        }
    }
    float* y = (float*)d_out;

    char* ws = (char*)d_ws;
    float*          Mbuf  = (float*)(ws + 0);
    unsigned short* Wqkvb = (unsigned short*)(ws + 4096);        // 3,145,728 B
    unsigned short* Woutb = (unsigned short*)(ws + 3149824);     // 1,048,576 B
    unsigned short* xt    = (unsigned short*)(ws + 4198400);     // 4,194,304 B
    unsigned short* qh    = (unsigned short*)(ws + 8392704);     // 8,388,608 B
    unsigned short* kh    = (unsigned short*)(ws + 16781312);    // 8,388,608 B
    unsigned short* vb    = (unsigned short*)(ws + 25169920);    // 8,388,608 B
    unsigned short* aot   = (unsigned short*)(ws + 33558528);    // 8,388,608 B -> 41,947,136

    k_prep<<<dim3(2048 + 512), 256, 0, stream>>>(Wqkv, Wout, x, qs, ks, Wqkvb, Woutb, xt, Mbuf);
    k_gemm_qkv<<<dim3(NSEQ / 128, ODIM / 128, BATCH), 256, 0, stream>>>(Wqkvb, xt, qs, ks, qh, kh, vb);
    k_attn<<<dim3(512), 512, 0, stream>>>(qh, kh, vb, aot, Mbuf);
    k_gemm_out<<<dim3(NSEQ / 64, CCH / 64, BATCH), 256, 0, stream>>>(Woutb, aot, bout, y);
}